// Round 3
// baseline (274.290 us; speedup 1.0000x reference)
//
#include <hip/hip_runtime.h>
#include <math.h>

// ---------------------------------------------------------------------------
// CausalSelfAttention  B=4 T=2048 C=1024 H=16 D=64, fp32 in/out.
// Round 11: attn iteration restructured for ILP + shared V fragments.
//   r10 post-mortem: gemm256 8-phase landed flat (21% MfmaUtil; 384-block
//   1-blk/CU fill <=75% + LDS-read-bound shape) -- revisit later with
//   counters. attn (~105us, MfmaUtil <1%) is the big idle kernel: per-iter
//   wall ~7900cyc vs ~2500cyc issued work. Stall = vf ds_reads interleaved
//   with consuming PV MFMAs (~400cyc raw LDS latency per process, x2 serial
//   processes re-reading the same V tile). Fix: per-iteration phase-dual
//   structure: {kf loads -> S-MFMA both frags (kf dies) -> vf loads issued
//   -> softmax both frags (hides vf latency) -> PV both frags vs shared vf}.
//   Halves vf LDS traffic, gives two independent VALU chains, keeps peak
//   arch VGPRs ~110 (<128 cap @ 4 blocks/CU). GEMMs unchanged (isolation).
// ---------------------------------------------------------------------------

typedef unsigned short ushort_t;
typedef __attribute__((ext_vector_type(8))) short bf16x8;   // 8 bf16 (4 VGPRs)
typedef __attribute__((ext_vector_type(4))) float f32x4;

#define MFMA16(a, b, c) __builtin_amdgcn_mfma_f32_16x16x32_bf16((a), (b), (c), 0, 0, 0)

#define CP_ASYNC16(lds, gp)                                                        \
    __builtin_amdgcn_global_load_lds(                                              \
        (const __attribute__((address_space(1))) void*)(gp),                       \
        (__attribute__((address_space(3))) void*)(lds), 16, 0, 0)

#define SCALE2 0.1803368801111204f   // 0.125 * log2(e): softmax in base-2

#define BAR() __builtin_amdgcn_s_barrier()
#define WAITBAR4()                                           \
    do {                                                     \
        asm volatile("s_waitcnt vmcnt(4)" ::: "memory");     \
        __builtin_amdgcn_s_barrier();                        \
    } while (0)
#define WAITBAR0()                                           \
    do {                                                     \
        asm volatile("s_waitcnt vmcnt(0)" ::: "memory");     \
        __builtin_amdgcn_s_barrier();                        \
    } while (0)

__device__ __forceinline__ ushort_t bf16r(float x) {
    unsigned int u = __float_as_uint(x);
    u += 0x7FFFu + ((u >> 16) & 1u);      // round-to-nearest-even
    return (ushort_t)(u >> 16);
}

// pack 2 f32 -> 2 bf16 in one u32 (RNE); no builtin on gfx950 -> inline asm
__device__ __forceinline__ unsigned cvt_pk_bf16(float lo, float hi) {
    unsigned r;
    asm("v_cvt_pk_bf16_f32 %0, %1, %2" : "=v"(r) : "v"(lo), "v"(hi));
    return r;
}
// a[32:63] <-> c[0:31]
__device__ __forceinline__ void pl32_swap(unsigned& a, unsigned& c) {
    asm("v_permlane32_swap_b32 %0, %1" : "+v"(a), "+v"(c));
}
// a[16:31] <-> c[0:15], a[48:63] <-> c[32:47]
__device__ __forceinline__ void pl16_swap(unsigned& a, unsigned& c) {
    asm("v_permlane16_swap_b32 %0, %1" : "+v"(a), "+v"(c));
}

// ---------------- prologue kernels ----------------

__global__ __launch_bounds__(256) void cast_f32_bf16(const float4* __restrict__ src,
                                                     ushort4* __restrict__ dst) {
    int i = blockIdx.x * 256 + threadIdx.x;
    float4 v = src[i];
    ushort4 o;
    o.x = bf16r(v.x); o.y = bf16r(v.y); o.z = bf16r(v.z); o.w = bf16r(v.w);
    dst[i] = o;
}

// src fp32 [R][Cc] -> dst bf16 [Cc][R]
__global__ __launch_bounds__(256) void transpose_cast(const float* __restrict__ src,
                                                      ushort_t* __restrict__ dst,
                                                      int R, int Cc) {
    __shared__ float tile[32][33];
    const int tx = threadIdx.x, ty = threadIdx.y;       // block (32,8)
    const int c0 = blockIdx.x * 32, r0 = blockIdx.y * 32;
#pragma unroll
    for (int i = 0; i < 4; ++i)
        tile[ty + i * 8][tx] = src[(size_t)(r0 + ty + i * 8) * Cc + c0 + tx];
    __syncthreads();
#pragma unroll
    for (int i = 0; i < 4; ++i)
        dst[(size_t)(c0 + ty + i * 8) * R + r0 + tx] = bf16r(tile[tx][ty + i * 8]);
}

// ---------------- 256x256 8-phase MFMA GEMM: C = A[M,K] @ Bt[N,K]^T -------
// 512 threads, 8 waves (wm = w>>2, wn = w&3), per-wave 128x64 output.
// LDS [2 dbuf][256 rows][64 k] bf16 for A and B = 128 KiB.
// Logical k-slot s (8 x 16B per row) stored at phys = s ^ (row&7):
// ds_read_b128 16-lane quarters then cover 32 banks 2-way (free).
// mode 0: scatter bf16 into Qh (pre-scaled) / Kh / Vt.  mode 1: fp32 Cout.
__global__ __launch_bounds__(512, 2)
void gemm256(const ushort_t* __restrict__ A, const ushort_t* __restrict__ Bt,
             int K, int mode,
             ushort_t* __restrict__ Qh, ushort_t* __restrict__ Kh,
             ushort_t* __restrict__ Vt, float* __restrict__ Cout, int nbx) {
    __shared__ __align__(16) ushort_t As[2][16384];
    __shared__ __align__(16) ushort_t Bs[2][16384];
    const int tid = threadIdx.x;
    const int l = tid & 63, w = tid >> 6;
    const int lm = l & 15, lq = l >> 4;
    const int wm = w >> 2, wn = w & 3;

    // XCD-aware swizzle (grid % 8 == 0 for all our launches)
    int bid = blockIdx.x;
    const int cpx = gridDim.x >> 3;
    bid = (bid & 7) * cpx + (bid >> 3);
    const int by = bid / nbx, bx = bid - by * nbx;
    const int row0 = by * 256, col0 = bx * 256;

    // staging: thread -> (srow 0..63, sslot 0..7); swizzle applied on src addr
    const int srow = tid >> 3, sslot = tid & 7;
    const int ssw = (sslot ^ (srow & 7)) * 8;
    const ushort_t* gA = A + (size_t)(row0 + srow) * K + ssw;
    const ushort_t* gB = Bt + (size_t)(col0 + srow) * K + ssw;

    auto stageA = [&](int dbuf, int hm, int T) {
        const ushort_t* s = gA + (size_t)(hm * 128) * K + T * 64;
        CP_ASYNC16(&As[dbuf][hm * 8192 + tid * 8], s);
        CP_ASYNC16(&As[dbuf][hm * 8192 + 4096 + tid * 8], s + (size_t)64 * K);
    };
    auto stageB = [&](int dbuf, int hm, int T) {
        const ushort_t* s = gB + (size_t)(hm * 128) * K + T * 64;
        CP_ASYNC16(&Bs[dbuf][hm * 8192 + tid * 8], s);
        CP_ASYNC16(&Bs[dbuf][hm * 8192 + 4096 + tid * 8], s + (size_t)64 * K);
    };

    const int arow0 = wm * 128 + lm;   // + qm*64 + mf*16
    const int brow0 = wn * 64 + lm;    // + qn*32 + nf*16
    const int lsw = lm & 7;            // == row&7 for every frag row

    f32x4 acc[8][4];
#pragma unroll
    for (int i = 0; i < 8; ++i)
#pragma unroll
        for (int j = 0; j < 4; ++j) acc[i][j] = (f32x4){0.f, 0.f, 0.f, 0.f};

    bf16x8 af[4][2];        // A frags, current qm half (reused across 2 phases)
    bf16x8 bq[2][2][2];     // B frags, both qn halves live

    auto ldA = [&](int d, int qm) {
#pragma unroll
        for (int mf = 0; mf < 4; ++mf) {
            const int r = arow0 + qm * 64 + mf * 16;
#pragma unroll
            for (int ks = 0; ks < 2; ++ks)
                af[mf][ks] =
                    *(const bf16x8*)(&As[d][r * 64 + (((ks << 2) | lq) ^ lsw) * 8]);
        }
    };
    auto ldB = [&](int d, int qn) {
#pragma unroll
        for (int nf = 0; nf < 2; ++nf) {
            const int r = brow0 + qn * 32 + nf * 16;
#pragma unroll
            for (int ks = 0; ks < 2; ++ks)
                bq[qn][nf][ks] =
                    *(const bf16x8*)(&Bs[d][r * 64 + (((ks << 2) | lq) ^ lsw) * 8]);
        }
    };
    auto mma = [&](int qm, int qn) {
        __builtin_amdgcn_s_setprio(1);
#pragma unroll
        for (int mf = 0; mf < 4; ++mf)
#pragma unroll
            for (int nf = 0; nf < 2; ++nf) {
                f32x4 c = acc[qm * 4 + mf][qn * 2 + nf];
                c = MFMA16(af[mf][0], bq[qn][nf][0], c);
                c = MFMA16(af[mf][1], bq[qn][nf][1], c);
                acc[qm * 4 + mf][qn * 2 + nf] = c;
            }
        __builtin_amdgcn_s_setprio(0);
    };

    // prologue: tile0 complete (8 loads), tile1 B-halves (4 loads)
    stageA(0, 0, 0); stageA(0, 1, 0);
    stageB(0, 0, 0); stageB(0, 1, 0);
    stageB(1, 0, 1); stageB(1, 1, 1);

    const int ntiles = K >> 6;
    const int niter = ntiles >> 1;

    for (int it = 0; it < niter; ++it) {
        const int tE = 2 * it, tO = tE + 1;
        const bool s2 = (tE + 2) < ntiles;
        const bool s3 = (tE + 3) < ntiles;

        // ---- K-tile even (dbuf 0) ----
        WAITBAR4();                       // tile tE landed (4 younger in flight)
        // g0: Q(0,0)
        ldA(0, 0); ldB(0, 0);
        stageA(1, 0, tO);
        BAR();
        mma(0, 0);
        BAR();
        // g1: Q(0,1)
        ldB(0, 1);
        stageA(1, 1, tO);
        BAR();
        mma(0, 1);
        BAR();
        // g2: Q(1,0)    (B reads of tile tE done end-g1 -> B halves reusable)
        ldA(0, 1);
        if (s2) stageB(0, 0, tE + 2);
        BAR();
        mma(1, 0);
        BAR();
        // g3: Q(1,1)
        if (s2) stageB(0, 1, tE + 2);
        BAR();
        mma(1, 1);
        BAR();

        // ---- K-tile odd (dbuf 1) ----
        if (it + 1 < niter) { WAITBAR4(); } else { WAITBAR0(); }
        // g4: Q(0,0)    (A reads of tile tE done end-g2 -> A halves reusable)
        ldA(1, 0); ldB(1, 0);
        if (s2) stageA(0, 0, tE + 2);
        BAR();
        mma(0, 0);
        BAR();
        // g5: Q(0,1)
        ldB(1, 1);
        if (s2) stageA(0, 1, tE + 2);
        BAR();
        mma(0, 1);
        BAR();
        // g6: Q(1,0)
        ldA(1, 1);
        if (s3) stageB(1, 0, tE + 3);
        BAR();
        mma(1, 0);
        BAR();
        // g7: Q(1,1)
        if (s3) stageB(1, 1, tE + 3);
        BAR();
        mma(1, 1);
        BAR();
    }

    // epilogue
    if (mode == 1) {
#pragma unroll
        for (int im = 0; im < 8; ++im)
#pragma unroll
            for (int in = 0; in < 4; ++in)
#pragma unroll
                for (int reg = 0; reg < 4; ++reg) {
                    const int rr = row0 + wm * 128 + im * 16 + lq * 4 + reg;
                    const int cc = col0 + wn * 64 + in * 16 + lm;
                    Cout[(size_t)rr * 1024 + cc] = acc[im][in][reg];
                }
    } else {
#pragma unroll
        for (int im = 0; im < 8; ++im) {
#pragma unroll
            for (int in = 0; in < 4; ++in) {
#pragma unroll
                for (int reg = 0; reg < 4; ++reg) {
                    const int rr = row0 + wm * 128 + im * 16 + lq * 4 + reg;
                    const int cc = col0 + wn * 64 + in * 16 + lm;
                    const float v = acc[im][in][reg];
                    const int b = rr >> 11, t = rr & 2047;
                    if (cc < 1024) {
                        const int h = cc >> 6, d = cc & 63;
                        Qh[((size_t)(b * 16 + h) * 2048 + t) * 64 + d] =
                            bf16r(v * SCALE2);          // fold softmax scale
                    } else if (cc < 2048) {
                        const int c2 = cc - 1024, h = c2 >> 6, d = c2 & 63;
                        Kh[((size_t)(b * 16 + h) * 2048 + t) * 64 + d] = bf16r(v);
                    } else {
                        const int c2 = cc - 2048, h = c2 >> 6, d = c2 & 63;
                        Vt[((size_t)(b * 16 + h) * 64 + d) * 2048 + t] = bf16r(v);
                    }
                }
            }
        }
    }
}

// ---------------- flash attention, MFMA, no-max softmax ----------------
// grid (64 bh, 16 pairs), 256 threads. Block handles q-tiles qbA=pr, qbB=31-pr
// against ONE k-stream 0..qbB; k-tiles <= qbA feed both q-frags.
// LDS: Ks 2x8KB dbuf + Vs 2x8KB dbuf = 32768 B.
// S^T = mfma(K,Q): lane holds P[k = n*16+lq*4+reg][q = w*16+lm];
// C-layout -> PV A-operand layout via cvt_pk + permlane swaps (in-register).
// Iteration is phase-dual: S both frags (kf dies) -> vf loads issued ->
// softmax both frags (hides vf LDS latency) -> PV both frags vs SHARED vf.
// 16B slot s of row r holds logical slot s ^ ((r>>1)&3): 0 bank conflicts.
__global__ __launch_bounds__(256, 4)
void attn_mfma(const ushort_t* __restrict__ Qh, const ushort_t* __restrict__ Kh,
               const ushort_t* __restrict__ Vt, ushort_t* __restrict__ Y) {
    __shared__ ushort_t Ks[2][4096];
    __shared__ ushort_t Vs[2][4096];
    const int tid = threadIdx.x, l = tid & 63, w = tid >> 6;
    const int lm = l & 15, lq = l >> 4;
    const int bh = blockIdx.x;                 // same bh -> shared L2 for K/V
    const int pr = blockIdx.y;                 // pair 0..15
    const int qbA = pr, qbB = 31 - pr;
    const int b = bh >> 4, h = bh & 15;
    const f32x4 zero4 = {0.f, 0.f, 0.f, 0.f};
    const short oneb = (short)0x3F80;          // bf16 1.0
    const bf16x8 onesf = {oneb, oneb, oneb, oneb, oneb, oneb, oneb, oneb};
    const int lqs8 = (lq ^ ((lm >> 1) & 3)) * 8;   // swizzled 16B slot offset

    // Q fragments for both tiles (Q pre-scaled by SCALE2)
    bf16x8 qf[2][2];
    {
        const ushort_t* qA = Qh + ((size_t)bh * 2048 + qbA * 64 + w * 16 + lm) * 64 + lq * 8;
        const ushort_t* qB = Qh + ((size_t)bh * 2048 + qbB * 64 + w * 16 + lm) * 64 + lq * 8;
        qf[0][0] = *(const bf16x8*)(qA);
        qf[0][1] = *(const bf16x8*)(qA + 32);
        qf[1][0] = *(const bf16x8*)(qB);
        qf[1][1] = *(const bf16x8*)(qB + 32);
    }

    f32x4 O[2][4], Ol[2];
#pragma unroll
    for (int q = 0; q < 2; ++q) {
        Ol[q] = zero4;
#pragma unroll
        for (int i = 0; i < 4; ++i) O[q][i] = zero4;
    }

    // DMA staging: thread -> row srow, 16B slot; swizzle applied on global src
    const int srow = tid >> 2, slot = tid & 3;
    const int srcoff = ((slot ^ ((srow >> 1) & 3)) * 8);
    const ushort_t* gKr = Kh + ((size_t)bh * 2048 + srow) * 64 + srcoff;  // +jb*4096
    const ushort_t* gVr = Vt + ((size_t)bh * 64 + srow) * 2048 + srcoff;  // +jb*64

    auto prefetch = [&](int jbn, int dbuf) {
        const ushort_t* gk = gKr + (size_t)jbn * 4096;
        const ushort_t* gv = gVr + jbn * 64;
        CP_ASYNC16(&Ks[dbuf][tid * 8], gk);
        CP_ASYNC16(&Ks[dbuf][2048 + tid * 8], gk + 32);
        CP_ASYNC16(&Vs[dbuf][tid * 8], gv);
        CP_ASYNC16(&Vs[dbuf][2048 + tid * 8], gv + 32);
    };

    // S^T for one q-frag (8 MFMA)
    auto sstep = [&](const bf16x8 (&kf)[4][2], const bf16x8 (&qfr)[2],
                     f32x4 (&st)[4]) {
#pragma unroll
        for (int n = 0; n < 4; ++n) {
            f32x4 s_acc = zero4;
            s_acc = MFMA16(kf[n][0], qfr[0], s_acc);
            s_acc = MFMA16(kf[n][1], qfr[1], s_acc);
            st[n] = s_acc;
        }
    };

    // exp2 softmax + in-register C-layout -> A-operand conversion
    auto softmax = [&](const f32x4 (&st)[4], bool diag,
                       bf16x8& pf0, bf16x8& pf1) {
        float p[4][4];
#pragma unroll
        for (int n = 0; n < 4; ++n)
#pragma unroll
            for (int reg = 0; reg < 4; ++reg)
                p[n][reg] = __builtin_amdgcn_exp2f(st[n][reg]);
        if (diag) {
            const int qloc = w * 16 + lm;
#pragma unroll
            for (int n = 0; n < 4; ++n)
#pragma unroll
                for (int reg = 0; reg < 4; ++reg)
                    if (n * 16 + lq * 4 + reg > qloc) p[n][reg] = 0.f;
        }
        unsigned cpk[4][2];
#pragma unroll
        for (int n = 0; n < 4; ++n) {
            cpk[n][0] = cvt_pk_bf16(p[n][0], p[n][1]);
            cpk[n][1] = cvt_pk_bf16(p[n][2], p[n][3]);
        }
        union U8 { unsigned u[4]; bf16x8 v; };
        {
            unsigned z00 = cpk[0][0], z10 = cpk[1][0];
            unsigned z01 = cpk[0][1], z11 = cpk[1][1];
            pl32_swap(z00, z10); pl16_swap(z00, z10);
            pl32_swap(z01, z11); pl16_swap(z01, z11);
            U8 t0; t0.u[0] = z00; t0.u[1] = z01; t0.u[2] = z10; t0.u[3] = z11;
            pf0 = t0.v;
            unsigned y00 = cpk[2][0], y10 = cpk[3][0];
            unsigned y01 = cpk[2][1], y11 = cpk[3][1];
            pl32_swap(y00, y10); pl16_swap(y00, y10);
            pl32_swap(y01, y11); pl16_swap(y01, y11);
            U8 t1; t1.u[0] = y00; t1.u[1] = y01; t1.u[2] = y10; t1.u[3] = y11;
            pf1 = t1.v;
        }
    };

    // PV for one q-frag against the shared vf (10 MFMA)
    auto pv = [&](const bf16x8& pf0, const bf16x8& pf1,
                  const bf16x8 (&vf)[4][2], f32x4 (&Or)[4], f32x4& Olr) {
#pragma unroll
        for (int dn = 0; dn < 4; ++dn) {
            Or[dn] = MFMA16(pf0, vf[dn][0], Or[dn]);
            Or[dn] = MFMA16(pf1, vf[dn][1], Or[dn]);
        }
        Olr = MFMA16(pf0, onesf, Olr);
        Olr = MFMA16(pf1, onesf, Olr);
    };

    prefetch(0, 0);
    for (int jb = 0; jb <= qbB; ++jb) {
        const int buf = jb & 1;
        __syncthreads();                   // own DMA drained; prev buf free
        if (jb < qbB) prefetch(jb + 1, buf ^ 1);

        const ushort_t* Kb = Ks[buf];
        const ushort_t* Vb = Vs[buf];
        const bool dual = (jb <= qbA);     // wave-uniform

        // K fragments (die after the S phase)
        bf16x8 kf[4][2];
#pragma unroll
        for (int n = 0; n < 4; ++n) {
            kf[n][0] = *(const bf16x8*)(Kb + (n * 16 + lm) * 32 + lqs8);
            kf[n][1] = *(const bf16x8*)(Kb + 2048 + (n * 16 + lm) * 32 + lqs8);
        }

        // ---- S phase: both frags ----
        f32x4 stB[4], stA[4];
        __builtin_amdgcn_s_setprio(1);
        sstep(kf, qf[1], stB);
        if (dual) sstep(kf, qf[0], stA);
        __builtin_amdgcn_s_setprio(0);

        // ---- issue shared V fragment loads; latency hides under softmax ----
        bf16x8 vf[4][2];
#pragma unroll
        for (int dn = 0; dn < 4; ++dn) {
            vf[dn][0] = *(const bf16x8*)(Vb + (dn * 16 + lm) * 32 + lqs8);
            vf[dn][1] = *(const bf16x8*)(Vb + 2048 + (dn * 16 + lm) * 32 + lqs8);
        }

        // ---- softmax phase: both frags (independent VALU chains) ----
        bf16x8 pfB0, pfB1, pfA0, pfA1;
        softmax(stB, jb == qbB, pfB0, pfB1);
        if (dual) softmax(stA, jb == qbA, pfA0, pfA1);

        // ---- PV phase: both frags vs shared vf ----
        __builtin_amdgcn_s_setprio(1);
        pv(pfB0, pfB1, vf, O[1], Ol[1]);
        if (dual) pv(pfA0, pfA1, vf, O[0], Ol[0]);
        __builtin_amdgcn_s_setprio(0);
    }

    // epilogue: y[b*2048+t][h*64+d] bf16
#pragma unroll
    for (int qs = 0; qs < 2; ++qs) {
        const int tq = (qs ? qbB : qbA) * 64;
#pragma unroll
        for (int reg = 0; reg < 4; ++reg) {
            const float inv = 1.f / Ol[qs][reg];
            const size_t row = (size_t)b * 2048 + tq + w * 16 + lq * 4 + reg;
#pragma unroll
            for (int dn = 0; dn < 4; ++dn)
                Y[row * 1024 + h * 64 + dn * 16 + lm] = bf16r(O[qs][dn][reg] * inv);
        }
    }
}

// ---------------- launch ----------------

extern "C" void kernel_launch(void* const* d_in, const int* in_sizes, int n_in,
                              void* d_out, int out_size, void* d_ws, size_t ws_size,
                              hipStream_t stream) {
    const float* x      = (const float*)d_in[0];   // [8192,1024]
    const float* w_attn = (const float*)d_in[1];   // [1024,3072]
    const float* w_proj = (const float*)d_in[2];   // [1024,1024]
    float* out = (float*)d_out;

    char* ws = (char*)d_ws;
    ushort_t* xb   = (ushort_t*)(ws);                       // 16 MB  [8192][1024]
    ushort_t* watT = (ushort_t*)(ws + 16777216);            // 6 MB   [3072][1024]
    ushort_t* wpjT = (ushort_t*)(ws + 23068672);            // 2 MB   [1024][1024]
    ushort_t* Qh   = (ushort_t*)(ws + 25165824);            // 16 MB  [b,h,t,d] (pre-scaled)
    ushort_t* Kh   = (ushort_t*)(ws + 41943040);            // 16 MB  [b,h,t,d]
    ushort_t* Vt   = (ushort_t*)(ws + 58720256);            // 16 MB  [b,h,d,t]
    ushort_t* Y    = (ushort_t*)(ws + 75497472);            // 16 MB  [8192][1024]

    hipLaunchKernelGGL(cast_f32_bf16, dim3(8192), dim3(256), 0, stream,
                       (const float4*)x, (ushort4*)xb);
    hipLaunchKernelGGL(transpose_cast, dim3(96, 32), dim3(32, 8), 0, stream,
                       w_attn, watT, 1024, 3072);
    hipLaunchKernelGGL(transpose_cast, dim3(32, 32), dim3(32, 8), 0, stream,
                       w_proj, wpjT, 1024, 1024);

    // QKV: M=8192 N=3072 -> 32x12 = 384 blocks
    hipLaunchKernelGGL(gemm256, dim3(384), dim3(512), 0, stream,
                       xb, watT, 1024, 0, Qh, Kh, Vt, (float*)nullptr, 12);

    hipLaunchKernelGGL(attn_mfma, dim3(64, 16), dim3(256), 0, stream,
                       Qh, Kh, Vt, Y);

    // proj: M=8192 N=1024 -> 32x4 = 128 blocks
    hipLaunchKernelGGL(gemm256, dim3(128), dim3(512), 0, stream,
                       Y, wpjT, 1024, 1, (ushort_t*)nullptr, (ushort_t*)nullptr,
                       (ushort_t*)nullptr, out, 4);
}

// Round 5
// 246.809 us; speedup vs baseline: 1.1113x; 1.1113x over previous
//
#include <hip/hip_runtime.h>
#include <math.h>

// ---------------------------------------------------------------------------
// CausalSelfAttention  B=4 T=2048 C=1024 H=16 D=64, fp32 in/out.
// Round 12 (resubmit; r12 bench hit GPUAcquisitionTimeout, no data).
//   attn reverted to r10 (r11 phase-dual regressed +11us, register
//   pressure). GEMM geometry changed for grid fill: BM=256 BN=128 BK=64,
//   512 thr (8 waves 4Mx2N, 64x64/wave), LDS 96KB. QKV: 32x24=768 blocks =
//   3 FULL rounds (was 384 = 1.5); proj: 32x8=256 = 1 full round (was 128 =
//   0.5). Same verified counted-vmcnt schedule, re-derived: 2 phases/K-tile,
//   16 MFMA each; 8 outstanding loads at every WAITBAR, retire 6 -> vmcnt(2);
//   stage slots: tile T's B staged 1.5 tiles early, A halves 1 tile early,
//   each overwrite after the barrier pair that retires its last ds_read.
// ---------------------------------------------------------------------------

typedef unsigned short ushort_t;
typedef __attribute__((ext_vector_type(8))) short bf16x8;   // 8 bf16 (4 VGPRs)
typedef __attribute__((ext_vector_type(4))) float f32x4;

#define MFMA16(a, b, c) __builtin_amdgcn_mfma_f32_16x16x32_bf16((a), (b), (c), 0, 0, 0)

#define CP_ASYNC16(lds, gp)                                                        \
    __builtin_amdgcn_global_load_lds(                                              \
        (const __attribute__((address_space(1))) void*)(gp),                       \
        (__attribute__((address_space(3))) void*)(lds), 16, 0, 0)

#define SCALE2 0.1803368801111204f   // 0.125 * log2(e): softmax in base-2

#define BAR() __builtin_amdgcn_s_barrier()
#define WAITBAR2()                                           \
    do {                                                     \
        asm volatile("s_waitcnt vmcnt(2)" ::: "memory");     \
        __builtin_amdgcn_s_barrier();                        \
    } while (0)
#define WAITBAR0()                                           \
    do {                                                     \
        asm volatile("s_waitcnt vmcnt(0)" ::: "memory");     \
        __builtin_amdgcn_s_barrier();                        \
    } while (0)

__device__ __forceinline__ ushort_t bf16r(float x) {
    unsigned int u = __float_as_uint(x);
    u += 0x7FFFu + ((u >> 16) & 1u);      // round-to-nearest-even
    return (ushort_t)(u >> 16);
}

// pack 2 f32 -> 2 bf16 in one u32 (RNE); no builtin on gfx950 -> inline asm
__device__ __forceinline__ unsigned cvt_pk_bf16(float lo, float hi) {
    unsigned r;
    asm("v_cvt_pk_bf16_f32 %0, %1, %2" : "=v"(r) : "v"(lo), "v"(hi));
    return r;
}
// a[32:63] <-> c[0:31]
__device__ __forceinline__ void pl32_swap(unsigned& a, unsigned& c) {
    asm("v_permlane32_swap_b32 %0, %1" : "+v"(a), "+v"(c));
}
// a[16:31] <-> c[0:15], a[48:63] <-> c[32:47]
__device__ __forceinline__ void pl16_swap(unsigned& a, unsigned& c) {
    asm("v_permlane16_swap_b32 %0, %1" : "+v"(a), "+v"(c));
}

// ---------------- prologue kernels ----------------

__global__ __launch_bounds__(256) void cast_f32_bf16(const float4* __restrict__ src,
                                                     ushort4* __restrict__ dst) {
    int i = blockIdx.x * 256 + threadIdx.x;
    float4 v = src[i];
    ushort4 o;
    o.x = bf16r(v.x); o.y = bf16r(v.y); o.z = bf16r(v.z); o.w = bf16r(v.w);
    dst[i] = o;
}

// src fp32 [R][Cc] -> dst bf16 [Cc][R]
__global__ __launch_bounds__(256) void transpose_cast(const float* __restrict__ src,
                                                      ushort_t* __restrict__ dst,
                                                      int R, int Cc) {
    __shared__ float tile[32][33];
    const int tx = threadIdx.x, ty = threadIdx.y;       // block (32,8)
    const int c0 = blockIdx.x * 32, r0 = blockIdx.y * 32;
#pragma unroll
    for (int i = 0; i < 4; ++i)
        tile[ty + i * 8][tx] = src[(size_t)(r0 + ty + i * 8) * Cc + c0 + tx];
    __syncthreads();
#pragma unroll
    for (int i = 0; i < 4; ++i)
        dst[(size_t)(c0 + ty + i * 8) * R + r0 + tx] = bf16r(tile[tx][ty + i * 8]);
}

// ---------------- 256x128 8-phase MFMA GEMM: C = A[M,K] @ Bt[N,K]^T -------
// 512 threads, 8 waves (wm = w>>1 in 0..3, wn = w&1), per-wave 64x64 output.
// LDS: As [2][256x64], Bs [2][128x64] bf16 = 96 KiB, 1 block/CU.
// Logical k-slot s (8 x 16B per row) stored at phys = s ^ (row&7):
// ds_read_b128 16-lane quarters cover 8 slots x 2 rows -> 2-way free.
// 2 phases per K-tile, 16 MFMA each. Counted vmcnt: 8 outstanding at each
// WAITBAR, retire 6 (current tile) -> vmcnt(2); vmcnt(0) only at last tile.
// mode 0: scatter bf16 into Qh (pre-scaled) / Kh / Vt.  mode 1: fp32 Cout.
__global__ __launch_bounds__(512, 2)
void gemm_8ph(const ushort_t* __restrict__ A, const ushort_t* __restrict__ Bt,
              int K, int mode,
              ushort_t* __restrict__ Qh, ushort_t* __restrict__ Kh,
              ushort_t* __restrict__ Vt, float* __restrict__ Cout, int nbx) {
    __shared__ __align__(16) ushort_t As[2][16384];   // 256 rows x 64 k
    __shared__ __align__(16) ushort_t Bs[2][8192];    // 128 rows x 64 k
    const int tid = threadIdx.x;
    const int l = tid & 63, w = tid >> 6;
    const int lm = l & 15, lq = l >> 4;
    const int wm = w >> 1, wn = w & 1;

    // XCD-aware swizzle (grid % 8 == 0 for all our launches)
    int bid = blockIdx.x;
    const int cpx = gridDim.x >> 3;
    bid = (bid & 7) * cpx + (bid >> 3);
    const int by = bid / nbx, bx = bid - by * nbx;
    const int row0 = by * 256, col0 = bx * 128;

    // staging: thread -> (srow 0..63, sslot 0..7); swizzle applied on src addr
    const int srow = tid >> 3, sslot = tid & 7;
    const int ssw = (sslot ^ (srow & 7)) * 8;
    const ushort_t* gA = A + (size_t)(row0 + srow) * K + ssw;
    const ushort_t* gB = Bt + (size_t)(col0 + srow) * K + ssw;

    auto stageA = [&](int dbuf, int hm, int T) {      // 128 rows = 2 sweeps
        const ushort_t* s = gA + (size_t)(hm * 128) * K + T * 64;
        CP_ASYNC16(&As[dbuf][hm * 8192 + tid * 8], s);
        CP_ASYNC16(&As[dbuf][hm * 8192 + 4096 + tid * 8], s + (size_t)64 * K);
    };
    auto stageB = [&](int dbuf, int T) {              // 128 rows = 2 sweeps
        const ushort_t* s = gB + T * 64;
        CP_ASYNC16(&Bs[dbuf][tid * 8], s);
        CP_ASYNC16(&Bs[dbuf][4096 + tid * 8], s + (size_t)64 * K);
    };

    const int arow0 = wm * 64 + lm;    // + qm*32 + mf*16
    const int brow0 = wn * 64 + lm;    // + qn*32 + nf*16
    const int lsw = lm & 7;            // == row&7 for every frag row

    f32x4 acc[4][4];                   // [qm*2+mf][qn*2+nf]
#pragma unroll
    for (int i = 0; i < 4; ++i)
#pragma unroll
        for (int j = 0; j < 4; ++j) acc[i][j] = (f32x4){0.f, 0.f, 0.f, 0.f};

    bf16x8 af[2][2];       // A frags of current qm half
    bf16x8 bq[2][2][2];    // B frags, whole 64-col wave span (both qn)

    auto ldA = [&](int d, int qm) {
#pragma unroll
        for (int mf = 0; mf < 2; ++mf) {
            const int r = arow0 + qm * 32 + mf * 16;
#pragma unroll
            for (int ks = 0; ks < 2; ++ks)
                af[mf][ks] =
                    *(const bf16x8*)(&As[d][r * 64 + (((ks << 2) | lq) ^ lsw) * 8]);
        }
    };
    auto ldB = [&](int d) {
#pragma unroll
        for (int qn = 0; qn < 2; ++qn)
#pragma unroll
            for (int nf = 0; nf < 2; ++nf) {
                const int r = brow0 + qn * 32 + nf * 16;
#pragma unroll
                for (int ks = 0; ks < 2; ++ks)
                    bq[qn][nf][ks] =
                        *(const bf16x8*)(&Bs[d][r * 64 + (((ks << 2) | lq) ^ lsw) * 8]);
            }
    };
    auto mma = [&](int qm) {           // 16 MFMA: current qm vs all 64 cols
        __builtin_amdgcn_s_setprio(1);
#pragma unroll
        for (int mf = 0; mf < 2; ++mf)
#pragma unroll
            for (int qn = 0; qn < 2; ++qn)
#pragma unroll
                for (int nf = 0; nf < 2; ++nf) {
                    f32x4 c = acc[qm * 2 + mf][qn * 2 + nf];
                    c = MFMA16(af[mf][0], bq[qn][nf][0], c);
                    c = MFMA16(af[mf][1], bq[qn][nf][1], c);
                    acc[qm * 2 + mf][qn * 2 + nf] = c;
                }
        __builtin_amdgcn_s_setprio(0);
    };

    // prologue: tile0 complete (6 loads) + tile1 B (2 loads) = 8 outstanding
    stageA(0, 0, 0); stageA(0, 1, 0);
    stageB(0, 0);
    stageB(1, 1);

    const int ntiles = K >> 6;         // 16 for K=1024 (even)
    const int niter = ntiles >> 1;

    for (int it = 0; it < niter; ++it) {
        const int tE = 2 * it, tO = tE + 1;
        const bool s2 = (tE + 2) < ntiles;
        const bool s3 = (tE + 3) < ntiles;

        // ---- K-tile even (dbuf 0) ----
        WAITBAR2();                    // tE landed; tO's B (2) stays in flight
        // pA
        ldA(0, 0); ldB(0);
        stageA(1, 0, tO);
        BAR();
        mma(0);
        BAR();
        // pB   (B[0] reads done end-pA -> B[0] reusable after this barrier)
        ldA(0, 1);
        stageA(1, 1, tO);
        if (s2) stageB(0, tE + 2);
        BAR();
        mma(1);
        BAR();

        // ---- K-tile odd (dbuf 1) ----
        if (it + 1 < niter) { WAITBAR2(); } else { WAITBAR0(); }
        // pC   (A[0] reads done end-pB -> A[0] halves reusable)
        ldA(1, 0); ldB(1);
        if (s2) stageA(0, 0, tE + 2);
        BAR();
        mma(0);
        BAR();
        // pD
        ldA(1, 1);
        if (s2) stageA(0, 1, tE + 2);
        if (s3) stageB(1, tE + 3);
        BAR();
        mma(1);
        BAR();
    }

    // epilogue
    if (mode == 1) {
#pragma unroll
        for (int im = 0; im < 4; ++im)
#pragma unroll
            for (int jn = 0; jn < 4; ++jn)
#pragma unroll
                for (int reg = 0; reg < 4; ++reg) {
                    const int rr = row0 + wm * 64 + im * 16 + lq * 4 + reg;
                    const int cc = col0 + wn * 64 + jn * 16 + lm;
                    Cout[(size_t)rr * 1024 + cc] = acc[im][jn][reg];
                }
    } else {
#pragma unroll
        for (int im = 0; im < 4; ++im) {
#pragma unroll
            for (int jn = 0; jn < 4; ++jn) {
#pragma unroll
                for (int reg = 0; reg < 4; ++reg) {
                    const int rr = row0 + wm * 64 + im * 16 + lq * 4 + reg;
                    const int cc = col0 + wn * 64 + jn * 16 + lm;
                    const float v = acc[im][jn][reg];
                    const int b = rr >> 11, t = rr & 2047;
                    if (cc < 1024) {
                        const int h = cc >> 6, d = cc & 63;
                        Qh[((size_t)(b * 16 + h) * 2048 + t) * 64 + d] =
                            bf16r(v * SCALE2);          // fold softmax scale
                    } else if (cc < 2048) {
                        const int c2 = cc - 1024, h = c2 >> 6, d = c2 & 63;
                        Kh[((size_t)(b * 16 + h) * 2048 + t) * 64 + d] = bf16r(v);
                    } else {
                        const int c2 = cc - 2048, h = c2 >> 6, d = c2 & 63;
                        Vt[((size_t)(b * 16 + h) * 64 + d) * 2048 + t] = bf16r(v);
                    }
                }
            }
        }
    }
}

// ---------------- flash attention, MFMA, no-max softmax (r10 version) ------
// grid (64 bh, 16 pairs), 256 threads. Block handles q-tiles qbA=pr, qbB=31-pr
// against ONE k-stream 0..qbB; k-tiles <= qbA feed both q-frags (kf shared).
// LDS: Ks 2x8KB dbuf + Vs 2x8KB dbuf = 32768 B.
// Softmax path is fully in-register: S^T = mfma(K,Q) puts q on the C-layout
// column (lane lm), k spread over the 4-lane group {lm,+16,+32,+48}.
// 16B slot s of row r holds logical slot s ^ ((r>>1)&3): 0 bank conflicts.
__global__ __launch_bounds__(256, 4)
void attn_mfma(const ushort_t* __restrict__ Qh, const ushort_t* __restrict__ Kh,
               const ushort_t* __restrict__ Vt, ushort_t* __restrict__ Y) {
    __shared__ ushort_t Ks[2][4096];
    __shared__ ushort_t Vs[2][4096];
    const int tid = threadIdx.x, l = tid & 63, w = tid >> 6;
    const int lm = l & 15, lq = l >> 4;
    const int bh = blockIdx.x;                 // same bh -> shared L2 for K/V
    const int pr = blockIdx.y;                 // pair 0..15
    const int qbA = pr, qbB = 31 - pr;
    const int b = bh >> 4, h = bh & 15;
    const f32x4 zero4 = {0.f, 0.f, 0.f, 0.f};
    const short oneb = (short)0x3F80;          // bf16 1.0
    const bf16x8 onesf = {oneb, oneb, oneb, oneb, oneb, oneb, oneb, oneb};
    const int lqs8 = (lq ^ ((lm >> 1) & 3)) * 8;   // swizzled 16B slot offset

    // Q fragments for both tiles (Q pre-scaled by SCALE2)
    bf16x8 qf[2][2];
    {
        const ushort_t* qA = Qh + ((size_t)bh * 2048 + qbA * 64 + w * 16 + lm) * 64 + lq * 8;
        const ushort_t* qB = Qh + ((size_t)bh * 2048 + qbB * 64 + w * 16 + lm) * 64 + lq * 8;
        qf[0][0] = *(const bf16x8*)(qA);
        qf[0][1] = *(const bf16x8*)(qA + 32);
        qf[1][0] = *(const bf16x8*)(qB);
        qf[1][1] = *(const bf16x8*)(qB + 32);
    }

    f32x4 O[2][4], Ol[2];
#pragma unroll
    for (int q = 0; q < 2; ++q) {
        Ol[q] = zero4;
#pragma unroll
        for (int i = 0; i < 4; ++i) O[q][i] = zero4;
    }

    // DMA staging: thread -> row srow, 16B slot; swizzle applied on global src
    const int srow = tid >> 2, slot = tid & 3;
    const int srcoff = ((slot ^ ((srow >> 1) & 3)) * 8);
    const ushort_t* gKr = Kh + ((size_t)bh * 2048 + srow) * 64 + srcoff;  // +jb*4096
    const ushort_t* gVr = Vt + ((size_t)bh * 64 + srow) * 2048 + srcoff;  // +jb*64

    auto prefetch = [&](int jbn, int dbuf) {
        const ushort_t* gk = gKr + (size_t)jbn * 4096;
        const ushort_t* gv = gVr + jbn * 64;
        CP_ASYNC16(&Ks[dbuf][tid * 8], gk);
        CP_ASYNC16(&Ks[dbuf][2048 + tid * 8], gk + 32);
        CP_ASYNC16(&Vs[dbuf][tid * 8], gv);
        CP_ASYNC16(&Vs[dbuf][2048 + tid * 8], gv + 32);
    };

    // one q-frag against the k-tile in Ks/Vs[buf]; kf passed in (shared).
    // S^T = mfma(K, Q): lane holds P[k = n*16+lq*4+reg][q = w*16+lm].
    auto process = [&](const bf16x8 (&kf)[4][2], const ushort_t* Vb,
                       const bf16x8 (&qfr)[2], f32x4 (&Or)[4], f32x4& Olr,
                       bool diag) {
        f32x4 st[4];
        __builtin_amdgcn_s_setprio(1);
#pragma unroll
        for (int n = 0; n < 4; ++n) {
            f32x4 s_acc = zero4;
            s_acc = MFMA16(kf[n][0], qfr[0], s_acc);
            s_acc = MFMA16(kf[n][1], qfr[1], s_acc);
            st[n] = s_acc;
        }
        __builtin_amdgcn_s_setprio(0);

        // p = exp2(s) directly (no max); mask only on diagonal tile
        float p[4][4];
#pragma unroll
        for (int n = 0; n < 4; ++n)
#pragma unroll
            for (int reg = 0; reg < 4; ++reg)
                p[n][reg] = __builtin_amdgcn_exp2f(st[n][reg]);
        if (diag) {
            const int qloc = w * 16 + lm;
#pragma unroll
            for (int n = 0; n < 4; ++n)
#pragma unroll
                for (int reg = 0; reg < 4; ++reg)
                    if (n * 16 + lq * 4 + reg > qloc) p[n][reg] = 0.f;
        }

        // pack to bf16 pairs: cpk[n][h] = {k = n*16+lq*4+2h, +1}
        unsigned cpk[4][2];
#pragma unroll
        for (int n = 0; n < 4; ++n) {
            cpk[n][0] = cvt_pk_bf16(p[n][0], p[n][1]);
            cpk[n][1] = cvt_pk_bf16(p[n][2], p[n][3]);
        }

        // 4-lane-group redistribution -> A-operand frags (k = lq*8..lq*8+7)
        union U8 { unsigned u[4]; bf16x8 v; };
        bf16x8 pf0, pf1;
        {
            unsigned z00 = cpk[0][0], z10 = cpk[1][0];
            unsigned z01 = cpk[0][1], z11 = cpk[1][1];
            pl32_swap(z00, z10); pl16_swap(z00, z10);
            pl32_swap(z01, z11); pl16_swap(z01, z11);
            U8 t0; t0.u[0] = z00; t0.u[1] = z01; t0.u[2] = z10; t0.u[3] = z11;
            pf0 = t0.v;
            unsigned y00 = cpk[2][0], y10 = cpk[3][0];
            unsigned y01 = cpk[2][1], y11 = cpk[3][1];
            pl32_swap(y00, y10); pl16_swap(y00, y10);
            pl32_swap(y01, y11); pl16_swap(y01, y11);
            U8 t1; t1.u[0] = y00; t1.u[1] = y01; t1.u[2] = y10; t1.u[3] = y11;
            pf1 = t1.v;
        }

        __builtin_amdgcn_s_setprio(1);
#pragma unroll
        for (int dn = 0; dn < 4; ++dn) {
            const bf16x8 vf0 = *(const bf16x8*)(Vb + (dn * 16 + lm) * 32 + lqs8);
            const bf16x8 vf1 = *(const bf16x8*)(Vb + 2048 + (dn * 16 + lm) * 32 + lqs8);
            Or[dn] = MFMA16(pf0, vf0, Or[dn]);
            Or[dn] = MFMA16(pf1, vf1, Or[dn]);
        }
        Olr = MFMA16(pf0, onesf, Olr);
        Olr = MFMA16(pf1, onesf, Olr);
        __builtin_amdgcn_s_setprio(0);
    };

    prefetch(0, 0);
    for (int jb = 0; jb <= qbB; ++jb) {
        const int buf = jb & 1;
        __syncthreads();                   // own DMA drained; prev buf free
        if (jb < qbB) prefetch(jb + 1, buf ^ 1);

        const ushort_t* Kb = Ks[buf];
        const ushort_t* Vb = Vs[buf];
        bf16x8 kf[4][2];
#pragma unroll
        for (int n = 0; n < 4; ++n) {
            kf[n][0] = *(const bf16x8*)(Kb + (n * 16 + lm) * 32 + lqs8);
            kf[n][1] = *(const bf16x8*)(Kb + 2048 + (n * 16 + lm) * 32 + lqs8);
        }

        process(kf, Vb, qf[1], O[1], Ol[1], jb == qbB);          // frag B
        if (jb <= qbA)
            process(kf, Vb, qf[0], O[0], Ol[0], jb == qbA);      // frag A
    }

    // epilogue: y[b*2048+t][h*64+d] bf16
#pragma unroll
    for (int qs = 0; qs < 2; ++qs) {
        const int tq = (qs ? qbB : qbA) * 64;
#pragma unroll
        for (int reg = 0; reg < 4; ++reg) {
            const float inv = 1.f / Ol[qs][reg];
            const size_t row = (size_t)b * 2048 + tq + w * 16 + lq * 4 + reg;
#pragma unroll
            for (int dn = 0; dn < 4; ++dn)
                Y[row * 1024 + h * 64 + dn * 16 + lm] = bf16r(O[qs][dn][reg] * inv);
        }
    }
}

// ---------------- launch ----------------

extern "C" void kernel_launch(void* const* d_in, const int* in_sizes, int n_in,
                              void* d_out, int out_size, void* d_ws, size_t ws_size,
                              hipStream_t stream) {
    const float* x      = (const float*)d_in[0];   // [8192,1024]
    const float* w_attn = (const float*)d_in[1];   // [1024,3072]
    const float* w_proj = (const float*)d_in[2];   // [1024,1024]
    float* out = (float*)d_out;

    char* ws = (char*)d_ws;
    ushort_t* xb   = (ushort_t*)(ws);                       // 16 MB  [8192][1024]
    ushort_t* watT = (ushort_t*)(ws + 16777216);            // 6 MB   [3072][1024]
    ushort_t* wpjT = (ushort_t*)(ws + 23068672);            // 2 MB   [1024][1024]
    ushort_t* Qh   = (ushort_t*)(ws + 25165824);            // 16 MB  [b,h,t,d] (pre-scaled)
    ushort_t* Kh   = (ushort_t*)(ws + 41943040);            // 16 MB  [b,h,t,d]
    ushort_t* Vt   = (ushort_t*)(ws + 58720256);            // 16 MB  [b,h,d,t]
    ushort_t* Y    = (ushort_t*)(ws + 75497472);            // 16 MB  [8192][1024]

    hipLaunchKernelGGL(cast_f32_bf16, dim3(8192), dim3(256), 0, stream,
                       (const float4*)x, (ushort4*)xb);
    hipLaunchKernelGGL(transpose_cast, dim3(96, 32), dim3(32, 8), 0, stream,
                       w_attn, watT, 1024, 3072);
    hipLaunchKernelGGL(transpose_cast, dim3(32, 32), dim3(32, 8), 0, stream,
                       w_proj, wpjT, 1024, 1024);

    // QKV: M=8192 N=3072 -> (8192/256)x(3072/128) = 32x24 = 768 blocks (3 rounds)
    hipLaunchKernelGGL(gemm_8ph, dim3(768), dim3(512), 0, stream,
                       xb, watT, 1024, 0, Qh, Kh, Vt, (float*)nullptr, 24);

    hipLaunchKernelGGL(attn_mfma, dim3(64, 16), dim3(256), 0, stream,
                       Qh, Kh, Vt, Y);

    // proj: M=8192 N=1024 -> 32x8 = 256 blocks (1 full round)
    hipLaunchKernelGGL(gemm_8ph, dim3(256), dim3(512), 0, stream,
                       Y, wpjT, 1024, 1, (ushort_t*)nullptr, (ushort_t*)nullptr,
                       (ushort_t*)nullptr, out, 8);
}